// Round 4
// baseline (1662.270 us; speedup 1.0000x reference)
//
#include <hip/hip_runtime.h>
#include <cstddef>

// ---------------------------------------------------------------------------
// Agent LSTM PPO forward, MI355X — round 4 (resubmit of round 3; bench infra
// timed out before the kernel ever ran — no counter evidence to act on).
//
//  * Only h_{S-1} feeds the head -> per-timestep dense stack is dead code.
//  * Batch rows are INDEPENDENT -> 32 wgs x 8 batch rows, each wg runs the
//    full hid=256 recurrence for its rows. ZERO inter-wg communication
//    (round 2 showed the L3 sync round-trip was ~85% of the step).
//  * Full W (384x1024) resident in registers as fp8 e4m3, pre-scaled x16:
//    192 VGPR/wave at 8 waves (2/SIMD, <=256 VGPR cap via launch_bounds).
//  * Gate GEMM: mfma_f32_16x16x32_fp8_fp8, A (comb = [x_t | h]) staged fp8
//    in LDS. A/B packed with the SAME k-byte-order -> k-permutation
//    invariant; C/D layout col=lane&15, row=(lane>>4)*4+q (m89, validated
//    in round 2).
//  * Nonlinearities: gates go acc -> LDS (dense remap, no idle lanes),
//    sigmoid/tanh via exp2 with log2e folded into bias and gate scale.
//  * Numerics: head attenuates h-perturbations ~1e4x (measured: rounds 1&2
//    both absmax 4.8e-7). fp8 h-error ~1e-2 -> predicted output ~2e-6.
// ---------------------------------------------------------------------------

#define S_LEN 512
#define OBS_D 128
#define HIDN  256
#define BATCH 256
#define ROWS  8            // batch rows per wg
#define NWG   32
#define ACT_DIM 32
#define CSTRIDE 400        // comb row stride (bytes, fp8): 384 + 16 pad
#define GSTRIDE 1028       // gates row stride (f32 words): 1024 + 4 pad

typedef float f32x4 __attribute__((ext_vector_type(4)));

#define L2E 1.4426950408889634f

__device__ __forceinline__ float sigexp2(float y) {
    // y pre-scaled by log2(e): sigmoid(x) = 1/(1+2^(-x*log2e))
    return __builtin_amdgcn_rcpf(1.0f + __builtin_amdgcn_exp2f(-y));
}

__global__ void __launch_bounds__(512, 2)
lstm_fused(const float* __restrict__ obs,
           const float* __restrict__ Wfp, const float* __restrict__ bfp,
           const float* __restrict__ Wip, const float* __restrict__ bip,
           const float* __restrict__ Wcp, const float* __restrict__ bcp,
           const float* __restrict__ Wop, const float* __restrict__ bop,
           float* __restrict__ hfinal)          // [BATCH][HIDN] f32
{
    __shared__ __align__(16) unsigned char comb[16][CSTRIDE]; // fp8 [x|h]
    __shared__ __align__(16) float gates[ROWS][GSTRIDE];      // scaled preacts
    __shared__ float biasL[1024];                             // bias * s_g

    const int tid  = threadIdx.x;
    const int wv   = tid >> 6;        // 8 waves; wave = batch row (nonlin/stage)
    const int lane = tid & 63;
    const int l15  = lane & 15, lg = lane >> 4;
    const int b0   = blockIdx.x * ROWS;

    // ---- stage scaled biases: biasL[g*256+j] = b_g[j]*s_g  (s_c = 2*log2e)
    {
        const float* Bg[4] = { bfp, bip, bcp, bop };
        for (int c = tid; c < 1024; c += 512) {
            const int g = c >> 8;
            biasL[c] = Bg[g][c & 255] * ((g == 2) ? 2.0f * L2E : L2E);
        }
    }
    // ---- zero comb (rows 8..15 stay zero forever -> M=8 padding)
    for (int i = tid; i < 16 * CSTRIDE / 4; i += 512)
        ((int*)comb)[i] = 0;

    // ---- one-time: full weight slice -> register fp8 B-fragments (x16) ----
    // wave wv owns gate-cols [wv*128, wv*128+128) = 8 tiles of 16.
    long long wfrag[8][12];
    {
        const float* Wg[4] = { Wfp, Wip, Wcp, Wop };
#pragma unroll
        for (int tile = 0; tile < 8; ++tile) {
            const int col = wv * 128 + tile * 16 + l15;
            const float* src = Wg[col >> 8] + (col & 255);
#pragma unroll
            for (int kk = 0; kk < 12; ++kk) {
                const int k0 = kk * 32 + lg * 8;
                int lo = 0, hi = 0;
                lo = __builtin_amdgcn_cvt_pk_fp8_f32(
                        src[(size_t)(k0 + 0) * HIDN] * 16.f,
                        src[(size_t)(k0 + 1) * HIDN] * 16.f, lo, false);
                lo = __builtin_amdgcn_cvt_pk_fp8_f32(
                        src[(size_t)(k0 + 2) * HIDN] * 16.f,
                        src[(size_t)(k0 + 3) * HIDN] * 16.f, lo, true);
                hi = __builtin_amdgcn_cvt_pk_fp8_f32(
                        src[(size_t)(k0 + 4) * HIDN] * 16.f,
                        src[(size_t)(k0 + 5) * HIDN] * 16.f, hi, false);
                hi = __builtin_amdgcn_cvt_pk_fp8_f32(
                        src[(size_t)(k0 + 6) * HIDN] * 16.f,
                        src[(size_t)(k0 + 7) * HIDN] * 16.f, hi, true);
                wfrag[tile][kk] = (long long)(unsigned)lo | ((long long)hi << 32);
            }
        }
    }

    f32x4 creg = { 0.f, 0.f, 0.f, 0.f };   // c-state: batch wv, hid 4*lane..+3

    // x prefetch (wave wv stages batch row wv; lane covers 2 obs elems)
    const float* xbase = obs + (size_t)(b0 + wv) * S_LEN * OBS_D + 2 * lane;
    float2 xv = *(const float2*)(xbase);    // t = 0

    __syncthreads();   // zero/bias visible before first stage/reads

#pragma unroll 1
    for (int t = 0; t < S_LEN; ++t) {
        // ---- stage x_t (fp8) + prefetch x_{t+1} --------------------------
        {
            const int p = __builtin_amdgcn_cvt_pk_fp8_f32(xv.x, xv.y, 0, false);
            *(short*)(&comb[wv][2 * lane]) = (short)p;
        }
        const int tn = (t + 1 < S_LEN) ? t + 1 : t;
        xv = *(const float2*)(xbase + (size_t)tn * OBS_D);
        __syncthreads();   // barrier A: comb (x_t + h_{t-1}) ready

        // ---- gate GEMM: 96 MFMAs/wave, B from registers ------------------
        f32x4 acc[8];
#pragma unroll
        for (int i = 0; i < 8; ++i) acc[i] = (f32x4){ 0.f, 0.f, 0.f, 0.f };
#pragma unroll
        for (int kk = 0; kk < 12; ++kk) {
            const long long a = *(const long long*)(&comb[l15][kk * 32 + lg * 8]);
#pragma unroll
            for (int tile = 0; tile < 8; ++tile)
                acc[tile] = __builtin_amdgcn_mfma_f32_16x16x32_fp8_fp8(
                                a, wfrag[tile][kk], acc[tile], 0, 0, 0);
        }

        // ---- store scaled gates y = acc*(s_g/16) + bias*s_g (rows 0..7) --
        if (lg < 2) {
#pragma unroll
            for (int tile = 0; tile < 8; ++tile) {
                const int col = wv * 128 + tile * 16 + l15;
                const float sg = ((col >> 8) == 2 ? 2.0f * L2E : L2E) * 0.0625f;
                const float bs = biasL[col];
#pragma unroll
                for (int q = 0; q < 4; ++q)
                    gates[lg * 4 + q][col] = fmaf(acc[tile][q], sg, bs);
            }
        }
        __syncthreads();   // barrier B: gates ready

        // ---- nonlin: wave wv = batch row wv; lane owns hid 4*lane..+3 ----
        {
            const f32x4 yf = *(const f32x4*)(&gates[wv][      4 * lane]);
            const f32x4 yi = *(const f32x4*)(&gates[wv][256 + 4 * lane]);
            const f32x4 yc = *(const f32x4*)(&gates[wv][512 + 4 * lane]);
            const f32x4 yo = *(const f32x4*)(&gates[wv][768 + 4 * lane]);
            f32x4 hv;
#pragma unroll
            for (int u = 0; u < 4; ++u) {
                const float f  = sigexp2(yf[u]);
                const float i  = sigexp2(yi[u]);
                const float cg = 2.0f * sigexp2(yc[u]) - 1.0f;   // tanh
                const float o  = sigexp2(yo[u]);
                creg[u] = f * creg[u] + i * cg;
                const float th = 2.0f * sigexp2(2.0f * L2E * creg[u]) - 1.0f;
                hv[u] = o * th;
            }
            int p = __builtin_amdgcn_cvt_pk_fp8_f32(hv[0], hv[1], 0, false);
            p     = __builtin_amdgcn_cvt_pk_fp8_f32(hv[2], hv[3], p, true);
            *(int*)(&comb[wv][OBS_D + 4 * lane]) = p;   // h region (fp8)
            if (t == S_LEN - 1)
                *(f32x4*)(&hfinal[(size_t)(b0 + wv) * HIDN + 4 * lane]) = hv;
        }
        // next iteration's barrier A orders comb writes vs MFMA reads
    }
}

// ---------------------------------------------------------------------------
// Head: z1=relu(h@W1+b1), z2=relu(z1@W2+b2), actor/critic, log_softmax.
// 64 wgs x 4 batch rows. ~0.24 GFLOP.
// ---------------------------------------------------------------------------
__device__ __forceinline__ float tanh_f(float x) {
    return 2.0f / (1.0f + __expf(-2.0f * x)) - 1.0f;
}

__global__ void __launch_bounds__(256)
head_kernel(const float* __restrict__ hfin,      // [BATCH][HIDN] f32
            const float* __restrict__ W1, const float* __restrict__ b1v,
            const float* __restrict__ W2, const float* __restrict__ b2v,
            const float* __restrict__ A1, const float* __restrict__ a1v,
            const float* __restrict__ A2, const float* __restrict__ a2v,
            const float* __restrict__ A3, const float* __restrict__ a3v,
            const float* __restrict__ C1, const float* __restrict__ c1v,
            const float* __restrict__ C2, const float* __restrict__ c2v,
            const float* __restrict__ C3, const float* __restrict__ c3v,
            const int* __restrict__ action,
            float* __restrict__ out)             // [3][BATCH]
{
    __shared__ float e0[4][HIDN];
    __shared__ float z1s[4][512];
    __shared__ float z2s[4][512];
    __shared__ float aL[4][64], vL[4][64], a2L[4][64], v2L[4][64];
    __shared__ float lgL[4][ACT_DIM];
    __shared__ float valL[4];

    const int tid = threadIdx.x;
    const int b0 = blockIdx.x * 4;

    for (int idx = tid; idx < 4 * HIDN; idx += 256) {
        const int r = idx >> 8, k = idx & 255;
        e0[r][k] = hfin[(size_t)(b0 + r) * HIDN + k];
    }
    __syncthreads();

    for (int i = 0; i < 8; ++i) {
        const int idx = i * 256 + tid;
        const int r = idx >> 9, cc = idx & 511;
        float acc = b1v[cc];
#pragma unroll 8
        for (int k = 0; k < HIDN; ++k) acc = fmaf(e0[r][k], W1[k * 512 + cc], acc);
        z1s[r][cc] = fmaxf(acc, 0.0f);
    }
    __syncthreads();

    for (int i = 0; i < 8; ++i) {
        const int idx = i * 256 + tid;
        const int r = idx >> 9, cc = idx & 511;
        float acc = b2v[cc];
#pragma unroll 8
        for (int k = 0; k < 512; ++k) acc = fmaf(z1s[r][k], W2[k * 512 + cc], acc);
        z2s[r][cc] = fmaxf(acc, 0.0f);
    }
    __syncthreads();

    {
        const int r = tid >> 6, j = tid & 63;
        float acc = a1v[j], accv = c1v[j];
#pragma unroll 8
        for (int k = 0; k < 512; ++k) {
            const float e = z2s[r][k];
            acc  = fmaf(e, A1[k * 64 + j], acc);
            accv = fmaf(e, C1[k * 64 + j], accv);
        }
        aL[r][j] = tanh_f(acc);
        vL[r][j] = tanh_f(accv);
    }
    __syncthreads();
    {
        const int r = tid >> 6, j = tid & 63;
        float acc = a2v[j], accv = c2v[j];
#pragma unroll 8
        for (int k = 0; k < 64; ++k) {
            acc  = fmaf(aL[r][k], A2[k * 64 + j], acc);
            accv = fmaf(vL[r][k], C2[k * 64 + j], accv);
        }
        a2L[r][j] = tanh_f(acc);
        v2L[r][j] = tanh_f(accv);
    }
    __syncthreads();
    if (tid < 128) {
        const int r = tid >> 5, j = tid & 31;
        float acc = a3v[j];
#pragma unroll 8
        for (int k = 0; k < 64; ++k) acc = fmaf(a2L[r][k], A3[k * ACT_DIM + j], acc);
        lgL[r][j] = acc;
    }
    if (tid >= 128 && tid < 132) {
        const int r = tid - 128;
        float acc = c3v[0];
#pragma unroll 8
        for (int k = 0; k < 64; ++k) acc = fmaf(v2L[r][k], C3[k], acc);
        valL[r] = acc;
    }
    __syncthreads();

    {
        const int wv = tid >> 6, lane = tid & 63;
        const float x = (lane < ACT_DIM) ? lgL[wv][lane] : -3.4e38f;
        float m = x;
        for (int off = 32; off; off >>= 1) m = fmaxf(m, __shfl_xor(m, off));
        const float p = (lane < ACT_DIM) ? __expf(x - m) : 0.0f;
        float s = p;
        for (int off = 32; off; off >>= 1) s += __shfl_xor(s, off);
        const float logs = logf(s);
        const float lp = x - m - logs;
        const int act = action[b0 + wv];
        float sel = (lane == act) ? lp : 0.0f;
        for (int off = 32; off; off >>= 1) sel += __shfl_xor(sel, off);
        float et = (lane < ACT_DIM) ? p * lp : 0.0f;
        for (int off = 32; off; off >>= 1) et += __shfl_xor(et, off);
        if (lane == 0) {
            const int b = b0 + wv;
            out[b]             = sel;
            out[BATCH + b]     = -et / s;
            out[2 * BATCH + b] = valL[wv];
        }
    }
}

extern "C" void kernel_launch(void* const* d_in, const int* in_sizes, int n_in,
                              void* d_out, int out_size, void* d_ws, size_t ws_size,
                              hipStream_t stream) {
    const float* obs = (const float*)d_in[0];
    const int*   action = (const int*)d_in[1];
    const float* Wfp = (const float*)d_in[2];  const float* bfp = (const float*)d_in[3];
    const float* Wip = (const float*)d_in[4];  const float* bip = (const float*)d_in[5];
    const float* Wcp = (const float*)d_in[6];  const float* bcp = (const float*)d_in[7];
    const float* Wop = (const float*)d_in[8];  const float* bop = (const float*)d_in[9];
    const float* W1  = (const float*)d_in[10]; const float* b1v = (const float*)d_in[11];
    const float* W2  = (const float*)d_in[12]; const float* b2v = (const float*)d_in[13];
    const float* A1  = (const float*)d_in[14]; const float* a1v = (const float*)d_in[15];
    const float* A2  = (const float*)d_in[16]; const float* a2v = (const float*)d_in[17];
    const float* A3  = (const float*)d_in[18]; const float* a3v = (const float*)d_in[19];
    const float* C1  = (const float*)d_in[20]; const float* c1v = (const float*)d_in[21];
    const float* C2  = (const float*)d_in[22]; const float* c2v = (const float*)d_in[23];
    const float* C3  = (const float*)d_in[24]; const float* c3v = (const float*)d_in[25];

    float* hfinal = (float*)d_ws;   // 256KB

    lstm_fused<<<dim3(NWG), dim3(512), 0, stream>>>(
        obs, Wfp, bfp, Wip, bip, Wcp, bcp, Wop, bop, hfinal);

    head_kernel<<<dim3(64), dim3(256), 0, stream>>>(
        hfinal, W1, b1v, W2, b2v, A1, a1v, A2, a2v, A3, a3v,
        C1, c1v, C2, c2v, C3, c3v, action, (float*)d_out);
}